// Round 11
// baseline (129.968 us; speedup 1.0000x reference)
//
#include <hip/hip_runtime.h>
#include <stdint.h>

#define CDIM 512
#define NPIX 1024
#define IDIM 64

// ws layout (ushort elements), ws_size = 256 MiB:
//   [0)       per-batch fgh: fT[1024][64] gT[1024][64] h[512][1024] bf16 (40 MB)
//   [XT_OFF)  xT[32][1024][512] fp16 + wh (dead after fg/h_mfma)
//   [LP_OFF)  Lp[4][32][1024] f32 partial row sums (512 KB)
#define WS_BATCH (65536 + 65536 + 524288)
#define XT_OFF   ((size_t)32 * WS_BATCH)
#define XT_ELEMS ((size_t)32 * 1024 * 512)
#define WH_OFF   (XT_OFF + XT_ELEMS)
#define P_ELEMS  ((size_t)32 * 1024 * 1024)
#define LP_OFF   (XT_OFF + P_ELEMS)

typedef __bf16 bf16x8 __attribute__((ext_vector_type(8)));
typedef _Float16 f16x8 __attribute__((ext_vector_type(8)));
typedef float f32x4 __attribute__((ext_vector_type(4)));

__device__ __forceinline__ unsigned short f2bf(float f) {
    union { float f; uint32_t u; } v; v.f = f;
    uint32_t u = v.u;
    u += 0x7fffu + ((u >> 16) & 1u);   // RNE
    return (unsigned short)(u >> 16);
}

__device__ __forceinline__ f32x4 mfma_bf(bf16x8 a, bf16x8 b, f32x4 c) {
    return __builtin_amdgcn_mfma_f32_16x16x32_bf16(a, b, c, 0, 0, 0);
}
__device__ __forceinline__ f32x4 mfma_h(f16x8 a, f16x8 b, f32x4 c) {
    return __builtin_amdgcn_mfma_f32_16x16x32_f16(a, b, c, 0, 0, 0);
}
__device__ __forceinline__ void gld_lds16(const void* g, void* l) {
    __builtin_amdgcn_global_load_lds(
        (const __attribute__((address_space(1))) unsigned int*)g,
        (__attribute__((address_space(3))) unsigned int*)l,
        16, 0, 0);
}
__device__ __forceinline__ void barrier_mem() {
    asm volatile("" ::: "memory");
    __builtin_amdgcn_s_barrier();
    asm volatile("" ::: "memory");
}
// LDS read-side swizzle for [rows][32-elem] 2B tiles (64B rows)
__device__ __forceinline__ int swz(int by) { return by ^ (((by >> 7) & 3) << 4); }

// ---------------------------------------------------------------------------
// Prep 1: W (fp32, 3 tensors) -> wh[640][512] fp16
// ---------------------------------------------------------------------------
__global__ __launch_bounds__(256) void wcvt(
    const float* __restrict__ Wf, const float* __restrict__ Wg,
    const float* __restrict__ Wh, _Float16* __restrict__ wh)
{
    int e = (blockIdx.x * 256 + threadIdx.x) * 4;
    int r = e >> 9, k = e & 511;
    const float* src;
    if (r < 64)       src = Wf + (size_t)r * 512 + k;
    else if (r < 128) src = Wg + (size_t)(r - 64) * 512 + k;
    else              src = Wh + (size_t)(r - 128) * 512 + k;
    float4 v = *(const float4*)src;
    _Float16 h4[4] = {(_Float16)v.x, (_Float16)v.y, (_Float16)v.z, (_Float16)v.w};
    *(ushort4*)(wh + e) = *(ushort4*)h4;
}

// ---------------------------------------------------------------------------
// Prep 2: x[b][c][n] fp32 -> xT[b][n][c] fp16 (LDS tile transpose 64x64)
// ---------------------------------------------------------------------------
__global__ __launch_bounds__(256) void xcvt(
    const float* __restrict__ x, _Float16* __restrict__ xT)
{
    __shared__ _Float16 tile[64][72];
    const int b = blockIdx.z, c0 = blockIdx.y * 64, n0 = blockIdx.x * 64;
    const int t = threadIdx.x;
    const float* xb = x + ((size_t)b * CDIM + c0) * NPIX + n0;
    #pragma unroll
    for (int p = 0; p < 4; ++p) {
        int ci = p * 16 + (t >> 4);
        int nj = (t & 15) * 4;
        float4 v = *(const float4*)(xb + (size_t)ci * NPIX + nj);
        tile[nj + 0][ci] = (_Float16)v.x;
        tile[nj + 1][ci] = (_Float16)v.y;
        tile[nj + 2][ci] = (_Float16)v.z;
        tile[nj + 3][ci] = (_Float16)v.w;
    }
    __syncthreads();
    _Float16* dst = xT + ((size_t)b * NPIX + n0) * CDIM + c0;
    #pragma unroll
    for (int p = 0; p < 2; ++p) {
        int n  = p * 32 + (t >> 3);
        int cc = (t & 7) * 8;
        ushort4 a  = *(ushort4*)&tile[n][cc];
        ushort4 bq = *(ushort4*)&tile[n][cc + 4];
        *(ushort4*)(dst + (size_t)n * CDIM + cc)     = a;
        *(ushort4*)(dst + (size_t)n * CDIM + cc + 4) = bq;
    }
}

// ---------------------------------------------------------------------------
// Kernel 1a: f/g projection (rows 0..127). Unchanged from round 10.
// ---------------------------------------------------------------------------
__global__ __launch_bounds__(256, 4) void fg_mfma(
    const _Float16* __restrict__ wh, const _Float16* __restrict__ xT,
    unsigned short* __restrict__ ws)
{
    const int orig = blockIdx.x;
    const int work = (orig & 7) * 32 + (orig >> 3);
    const int b    = work >> 3;
    const int tn   = work & 7;

    const int t = threadIdx.x, lane = t & 63, w = t >> 6;
    const int lr = lane & 15, lg = lane >> 4;
    const int wr = w >> 1, wc = w & 1;

    __shared__ _Float16 Abuf[2][128 * 32];
    __shared__ _Float16 Bbuf[2][128 * 32];

    const _Float16* Ag = wh;
    const _Float16* Bg = xT + ((size_t)b * NPIX + tn * 128) * CDIM;

    int offA[4], offB[4];
    #pragma unroll
    for (int mf = 0; mf < 4; ++mf)
        offA[mf] = swz((wr * 64 + mf * 16 + lr) * 64 + lg * 16);
    #pragma unroll
    for (int nf = 0; nf < 4; ++nf)
        offB[nf] = swz((wc * 64 + nf * 16 + lr) * 64 + lg * 16);

    f32x4 acc[4][4];
    #pragma unroll
    for (int i = 0; i < 4; ++i)
        #pragma unroll
        for (int j = 0; j < 4; ++j) acc[i][j] = (f32x4){0.f, 0.f, 0.f, 0.f};

    auto stage = [&](int buf, int k0) {
        #pragma unroll
        for (int p = 0; p < 2; ++p) {
            int q = p * 256 + t;
            gld_lds16(Ag + (size_t)(q >> 2) * CDIM + k0 + ((q & 3) ^ ((q >> 3) & 3)) * 8,
                      (char*)&Abuf[buf][0] + q * 16);
        }
        #pragma unroll
        for (int p = 0; p < 2; ++p) {
            int q = p * 256 + t;
            gld_lds16(Bg + (size_t)(q >> 2) * CDIM + k0 + ((q & 3) ^ ((q >> 3) & 3)) * 8,
                      (char*)&Bbuf[buf][0] + q * 16);
        }
    };

    stage(0, 0);
    stage(1, 32);

    #pragma unroll 1
    for (int ks = 0; ks < 16; ++ks) {
        const int cur = ks & 1;
        if (ks < 15) asm volatile("s_waitcnt vmcnt(4)" ::: "memory");
        else         asm volatile("s_waitcnt vmcnt(0)" ::: "memory");
        barrier_mem();

        const char* Ab = (const char*)&Abuf[cur][0];
        const char* Bb = (const char*)&Bbuf[cur][0];
        f16x8 af[4];
        #pragma unroll
        for (int mf = 0; mf < 4; ++mf)
            af[mf] = *(const f16x8*)(Ab + offA[mf]);
        #pragma unroll
        for (int nf = 0; nf < 4; ++nf) {
            f16x8 bv = *(const f16x8*)(Bb + offB[nf]);
            #pragma unroll
            for (int mf = 0; mf < 4; ++mf)
                acc[mf][nf] = mfma_h(af[mf], bv, acc[mf][nf]);
        }

        barrier_mem();
        if (ks + 2 < 16) stage(cur, (ks + 2) * 32);
    }

    unsigned short* base = ws + (size_t)b * WS_BATCH;
    const int nbase = tn * 128 + wc * 64;
    unsigned short* dst = base + (wr ? 65536 : 0);
    #pragma unroll
    for (int mf = 0; mf < 4; ++mf) {
        const int i0 = mf * 16 + lg * 4;
        #pragma unroll
        for (int nf = 0; nf < 4; ++nf) {
            int n = nbase + nf * 16 + lr;
            ushort4 v;
            v.x = f2bf(acc[mf][nf][0]); v.y = f2bf(acc[mf][nf][1]);
            v.z = f2bf(acc[mf][nf][2]); v.w = f2bf(acc[mf][nf][3]);
            *(ushort4*)(dst + (size_t)n * 64 + i0) = v;
        }
    }
}

// ---------------------------------------------------------------------------
// Kernel 1b (8-phase): h projection (rows 128..639). Unchanged from round 10.
// ---------------------------------------------------------------------------
__global__ __launch_bounds__(512, 2) void h_mfma(
    const _Float16* __restrict__ wh, const _Float16* __restrict__ xT,
    unsigned short* __restrict__ ws)
{
    const int orig = blockIdx.x;
    const int work = (orig & 7) * 32 + (orig >> 3);
    const int b    = work >> 3;
    const int tile = work & 7;
    const int m0   = (tile >> 2) * 256;
    const int n0   = (tile & 3) * 256;

    const int t = threadIdx.x, lane = t & 63, w = t >> 6;
    const int lr = lane & 15, lg = lane >> 4;
    const int wr = w >> 2, wc = w & 3;

    __shared__ __align__(16) char smem[131072];

    const _Float16* Ag = wh + (size_t)(128 + m0) * CDIM;
    const _Float16* Bg = xT + ((size_t)b * NPIX + n0) * CDIM;

    const int sk0 = ((lg) ^ (lr & 7)) * 16;
    const int sk1 = ((4 + lg) ^ (lr & 7)) * 16;
    const int rAbase = (wr * 128 + lr) * 128;
    const int rBbase = (wc * 64 + lr) * 128;

    f32x4 acc[8][4];
    #pragma unroll
    for (int i = 0; i < 8; ++i)
        #pragma unroll
        for (int j = 0; j < 4; ++j) acc[i][j] = (f32x4){0.f, 0.f, 0.f, 0.f};

    auto stage_half = [&](int buf, int isB, int half, int kt) {
        const _Float16* G = isB ? Bg : Ag;
        char* L = smem + isB * 65536 + buf * 32768 + half * 16384;
        #pragma unroll
        for (int l = 0; l < 2; ++l) {
            int q = l * 512 + t;
            gld_lds16(G + (size_t)(half * 128 + (q >> 3)) * CDIM + kt * 64
                        + (((q & 7) ^ ((q >> 3) & 7)) * 8),
                      L + q * 16);
        }
    };

    stage_half(0, 0, 0, 0); stage_half(0, 0, 1, 0);
    stage_half(0, 1, 0, 0); stage_half(0, 1, 1, 0);
    stage_half(1, 1, 0, 1); stage_half(1, 1, 1, 1);
    asm volatile("s_waitcnt vmcnt(4)" ::: "memory");
    barrier_mem();

    f16x8 bfr[4][2];

    #pragma unroll 1
    for (int j = 0; j < 4; ++j) {
        const bool nl = (j < 3);
        #pragma unroll
        for (int grp = 0; grp < 2; ++grp) {
            const char* Abase = smem + grp * 32768;
            const char* Bbase = smem + 65536 + grp * 32768;
            #pragma unroll
            for (int p = 0; p < 4; ++p) {
                if (p == 0) {
                    #pragma unroll
                    for (int nf = 0; nf < 4; ++nf) {
                        bfr[nf][0] = *(const f16x8*)(Bbase + rBbase + nf * 2048 + sk0);
                        bfr[nf][1] = *(const f16x8*)(Bbase + rBbase + nf * 2048 + sk1);
                    }
                }
                f16x8 af[2][2];
                #pragma unroll
                for (int e = 0; e < 2; ++e) {
                    af[e][0] = *(const f16x8*)(Abase + rAbase + (p * 2 + e) * 2048 + sk0);
                    af[e][1] = *(const f16x8*)(Abase + rAbase + (p * 2 + e) * 2048 + sk1);
                }
                if (grp == 0) {
                    if (p == 0) stage_half(1, 0, 0, 2 * j + 1);
                    if (p == 1) stage_half(1, 0, 1, 2 * j + 1);
                    if (p == 2 && nl) stage_half(0, 1, 0, 2 * j + 2);
                    if (p == 3 && nl) stage_half(0, 1, 1, 2 * j + 2);
                } else {
                    if (p == 0 && nl) stage_half(0, 0, 0, 2 * j + 2);
                    if (p == 1 && nl) stage_half(0, 0, 1, 2 * j + 2);
                    if (p == 2 && nl) stage_half(1, 1, 0, 2 * j + 3);
                    if (p == 3 && nl) stage_half(1, 1, 1, 2 * j + 3);
                }
                if (p == 3) {
                    if (nl) asm volatile("s_waitcnt vmcnt(4)" ::: "memory");
                    else    asm volatile("s_waitcnt vmcnt(0)" ::: "memory");
                }
                barrier_mem();
                __builtin_amdgcn_s_setprio(1);
                #pragma unroll
                for (int ks = 0; ks < 2; ++ks)
                    #pragma unroll
                    for (int e = 0; e < 2; ++e)
                        #pragma unroll
                        for (int nf = 0; nf < 4; ++nf)
                            acc[p * 2 + e][nf] =
                                mfma_h(af[e][ks], bfr[nf][ks], acc[p * 2 + e][nf]);
                __builtin_amdgcn_s_setprio(0);
            }
        }
    }

    unsigned short* hd = ws + (size_t)b * WS_BATCH + 131072;
    #pragma unroll
    for (int mf = 0; mf < 8; ++mf)
        #pragma unroll
        for (int nf = 0; nf < 4; ++nf) {
            int n = n0 + wc * 64 + nf * 16 + lr;
            #pragma unroll
            for (int j = 0; j < 4; ++j) {
                int c = m0 + wr * 128 + mf * 16 + lg * 4 + j;
                hd[(size_t)c * NPIX + n] = f2bf(acc[mf][nf][j]);
            }
        }
}

// ---------------------------------------------------------------------------
// Kernel 2: row sums only. Lp[nt][b][m] = sum over n-quarter of exp(g^T f).
// attn_sm (verified) minus the P~ store.
// ---------------------------------------------------------------------------
__global__ __launch_bounds__(256, 3) void attn_lp(
    const unsigned short* __restrict__ ws, float* __restrict__ Lp)
{
    const int orig = blockIdx.x;
    const int work = (orig & 7) * 256 + (orig >> 3);
    const int b    = work >> 6;
    const int tile = work & 63;
    const int mt = tile >> 2, nt = tile & 3;
    const int m0 = mt * 64, n0 = nt * 256;

    const int t = threadIdx.x, lane = t & 63, w = t >> 6;
    const int lr = lane & 15, lg = lane >> 4;

    const unsigned short* fT = ws + (size_t)b * WS_BATCH;
    const unsigned short* gT = fT + 65536;

    __shared__ unsigned short Ab[2][64 * 32];
    __shared__ unsigned short Bb[2][256 * 32];
    __shared__ float red[4][64];

    #pragma unroll
    for (int kc = 0; kc < 2; ++kc) {
        {
            int q = t;
            gld_lds16(gT + (size_t)(m0 + (q >> 2)) * 64 + kc * 32 + ((q & 3) ^ ((q >> 3) & 3)) * 8,
                      (char*)&Ab[kc][0] + q * 16);
        }
        #pragma unroll
        for (int p = 0; p < 4; ++p) {
            int q = p * 256 + t;
            gld_lds16(fT + (size_t)(n0 + (q >> 2)) * 64 + kc * 32 + ((q & 3) ^ ((q >> 3) & 3)) * 8,
                      (char*)&Bb[kc][0] + q * 16);
        }
    }
    __syncthreads();

    int offA[4], offB[4];
    #pragma unroll
    for (int mf = 0; mf < 4; ++mf)
        offA[mf] = swz((mf * 16 + lr) * 64 + lg * 16);
    #pragma unroll
    for (int nf = 0; nf < 4; ++nf)
        offB[nf] = swz((w * 64 + nf * 16 + lr) * 64 + lg * 16);

    f32x4 acc[4][4];
    #pragma unroll
    for (int i = 0; i < 4; ++i)
        #pragma unroll
        for (int j = 0; j < 4; ++j) acc[i][j] = (f32x4){0.f, 0.f, 0.f, 0.f};

    #pragma unroll
    for (int kc = 0; kc < 2; ++kc) {
        const char* Abc = (const char*)&Ab[kc][0];
        const char* Bbc = (const char*)&Bb[kc][0];
        bf16x8 af[4];
        #pragma unroll
        for (int mf = 0; mf < 4; ++mf)
            af[mf] = *(const bf16x8*)(Abc + offA[mf]);
        #pragma unroll
        for (int nf = 0; nf < 4; ++nf) {
            bf16x8 bv = *(const bf16x8*)(Bbc + offB[nf]);
            #pragma unroll
            for (int mf = 0; mf < 4; ++mf)
                acc[mf][nf] = mfma_bf(af[mf], bv, acc[mf][nf]);
        }
    }

    #pragma unroll
    for (int mf = 0; mf < 4; ++mf) {
        #pragma unroll
        for (int j = 0; j < 4; ++j) {
            float s = 0.f;
            #pragma unroll
            for (int nf = 0; nf < 4; ++nf)
                s += __expf(acc[mf][nf][j]);
            s += __shfl_xor(s, 1);
            s += __shfl_xor(s, 2);
            s += __shfl_xor(s, 4);
            s += __shfl_xor(s, 8);
            if (lr == 0) red[w][mf * 16 + lg * 4 + j] = s;
        }
    }
    __syncthreads();
    if (t < 64) {
        float s = red[0][t] + red[1][t] + red[2][t] + red[3][t];
        Lp[(size_t)nt * 32768 + (size_t)b * 1024 + m0 + t] = s;
    }
}

// ---------------------------------------------------------------------------
// Kernel 3 (FUSED): O[m][c] = (1/L[m]) sum_n exp(g^T f)[m][n] h[c][n].
// Block 256m x 256c, 512 thr = 8 waves. Loop 16 n-tiles of 64:
//   QK^T (g persistent in LDS, f dbuf) -> exp -> P-tile in LDS (pitch 160B,
//   conflict-free writes) -> PV MFMA (h dbuf). P~ never touches global.
// Staging leads: h 1 iter, f 2 iters; counted vmcnt(5); lgkmcnt(0)+barrier.
// Grid 256 = 8 XCD x (4 batches x {4 mt x 2 ct}) = 1 block/CU. LDS 152 KB.
// ---------------------------------------------------------------------------
__global__ __launch_bounds__(512, 2) void attn_fused(
    const unsigned short* __restrict__ ws, const float* __restrict__ Lp,
    float* __restrict__ out)
{
    const int orig = blockIdx.x;
    const int work = (orig & 7) * 32 + (orig >> 3);
    const int b    = work >> 3;
    const int tile = work & 7;                 // 4 mt x 2 ct
    const int m0   = (tile >> 1) * 256;
    const int c0   = (tile & 1) * 256;

    const int t = threadIdx.x, lane = t & 63, w = t >> 6;
    const int lr = lane & 15, lg = lane >> 4;
    const int wr = w >> 2;        // m-half (2) for both QK and PV
    const int wq = w & 3;         // QK n-quarter / PV c-quarter (4)

    const unsigned short* fT = ws + (size_t)b * WS_BATCH;   // f [1024][64]
    const unsigned short* gT = fT + 65536;                   // g [1024][64]
    const unsigned short* hg = fT + 131072;                  // h [512][1024]

    // LDS: g[256][64] @0 (32K) | f[64][64] x2 @32768 (16K) |
    //      h[256][64] x2 @49152 (64K) | P[256] rows x 160B @114688 (40K)
    __shared__ __align__(16) char smem[155648];
    unsigned short* Pl = (unsigned short*)(smem + 114688);

    const int sk0 = ((lg) ^ (lr & 7)) * 16;
    const int sk1 = ((4 + lg) ^ (lr & 7)) * 16;

    f32x4 acc[8][4];
    #pragma unroll
    for (int i = 0; i < 8; ++i)
        #pragma unroll
        for (int j = 0; j < 4; ++j) acc[i][j] = (f32x4){0.f, 0.f, 0.f, 0.f};

    auto stage_g = [&]() {   // [256 m][64k], rows 128B, src slot pre-swizzled
        #pragma unroll
        for (int l = 0; l < 4; ++l) {
            int q = l * 512 + t;
            gld_lds16(gT + (size_t)(m0 + (q >> 3)) * 64 + (((q & 7) ^ ((q >> 3) & 7)) * 8),
                      smem + q * 16);
        }
    };
    auto stage_f = [&](int buf, int nt) {   // [64 n][64k]
        int q = t;
        gld_lds16(fT + (size_t)(nt * 64 + (q >> 3)) * 64 + (((q & 7) ^ ((q >> 3) & 7)) * 8),
                  smem + 32768 + buf * 8192 + q * 16);
    };
    auto stage_h = [&](int buf, int nt) {   // [256 c][64 n]
        #pragma unroll
        for (int l = 0; l < 4; ++l) {
            int q = l * 512 + t;
            gld_lds16(hg + (size_t)(c0 + (q >> 3)) * NPIX + nt * 64
                         + (((q & 7) ^ ((q >> 3) & 7)) * 8),
                      smem + 49152 + buf * 32768 + q * 16);
        }
    };

    // prologue: g + f(0) + h(0) + f(1); wait all but f(1)
    stage_g();
    stage_f(0, 0);
    stage_h(0, 0);
    stage_f(1, 1);
    asm volatile("s_waitcnt vmcnt(1)" ::: "memory");
    barrier_mem();

    #pragma unroll 1
    for (int nt = 0; nt < 16; ++nt) {
        // ---- issue h(nt+1): hbuf[(nt+1)&1] free since end of nt-1 ----
        if (nt + 1 < 16) stage_h((nt + 1) & 1, nt + 1);

        // ---- QK^T: S (wave: 128m x 16n) ----
        const char* fb = smem + 32768 + (nt & 1) * 8192;
        bf16x8 qb0 = *(const bf16x8*)(fb + (wq * 16 + lr) * 128 + sk0);
        bf16x8 qb1 = *(const bf16x8*)(fb + (wq * 16 + lr) * 128 + sk1);
        f32x4 sacc[8];
        #pragma unroll
        for (int mf = 0; mf < 8; ++mf) {
            const char* ga = smem + (wr * 128 + mf * 16 + lr) * 128;
            bf16x8 a0 = *(const bf16x8*)(ga + sk0);
            bf16x8 a1 = *(const bf16x8*)(ga + sk1);
            f32x4 z = {0.f, 0.f, 0.f, 0.f};
            z = mfma_bf(a0, qb0, z);
            sacc[mf] = mfma_bf(a1, qb1, z);
        }
        // ---- exp -> P_lds (pitch 80 ushorts = 160 B; conflict-free) ----
        #pragma unroll
        for (int mf = 0; mf < 8; ++mf) {
            const int row = wr * 128 + mf * 16 + lg * 4;
            #pragma unroll
            for (int j = 0; j < 4; ++j)
                Pl[(row + j) * 80 + wq * 16 + lr] = f2bf(__expf(sacc[mf][j]));
        }
        asm volatile("s_waitcnt lgkmcnt(0)" ::: "memory");
        barrier_mem();   // B1: P writes visible; all f-reads done

        // ---- issue f(nt+2) into the f-buffer just freed ----
        if (nt + 2 < 16) stage_f(nt & 1, nt + 2);

        // ---- gate: h(nt) and f(nt+1) must be landed ----
        if (nt < 14)       asm volatile("s_waitcnt vmcnt(5)" ::: "memory");
        else if (nt == 14) asm volatile("s_waitcnt vmcnt(4)" ::: "memory");
        else               asm volatile("s_waitcnt vmcnt(0)" ::: "memory");

        // ---- PV: O += P x h^T (wave: 128m x 64c) ----
        const char* hb_ = smem + 49152 + (nt & 1) * 32768;
        bf16x8 hb[4][2];
        #pragma unroll
        for (int nf = 0; nf < 4; ++nf) {
            hb[nf][0] = *(const bf16x8*)(hb_ + (wq * 64 + nf * 16 + lr) * 128 + sk0);
            hb[nf][1] = *(const bf16x8*)(hb_ + (wq * 64 + nf * 16 + lr) * 128 + sk1);
        }
        __builtin_amdgcn_s_setprio(1);
        #pragma unroll
        for (int p = 0; p < 4; ++p) {
            bf16x8 af[2][2];
            #pragma unroll
            for (int e = 0; e < 2; ++e) {
                const char* pa = (const char*)Pl + (wr * 128 + (p * 2 + e) * 16 + lr) * 160;
                af[e][0] = *(const bf16x8*)(pa + lg * 16);
                af[e][1] = *(const bf16x8*)(pa + 64 + lg * 16);
            }
            #pragma unroll
            for (int ks = 0; ks < 2; ++ks)
                #pragma unroll
                for (int e = 0; e < 2; ++e)
                    #pragma unroll
                    for (int nf = 0; nf < 4; ++nf)
                        acc[p * 2 + e][nf] =
                            mfma_bf(af[e][ks], hb[nf][ks], acc[p * 2 + e][nf]);
        }
        __builtin_amdgcn_s_setprio(0);
        asm volatile("s_waitcnt lgkmcnt(0)" ::: "memory");
        barrier_mem();   // B2: P reads done before next iteration overwrites
    }

    // epilogue: divide by row sum L[m] (verbatim attn_pv)
    #pragma unroll
    for (int mf = 0; mf < 8; ++mf) {
        const size_t mi = (size_t)b * 1024 + m0 + wr * 128 + mf * 16 + lg * 4;
        f32x4 L = *(const f32x4*)&Lp[mi]
                + *(const f32x4*)&Lp[32768 + mi]
                + *(const f32x4*)&Lp[65536 + mi]
                + *(const f32x4*)&Lp[98304 + mi];
        f32x4 rinv;
        #pragma unroll
        for (int j = 0; j < 4; ++j) rinv[j] = 1.0f / L[j];
        #pragma unroll
        for (int nf = 0; nf < 4; ++nf) {
            f32x4 o = acc[mf][nf] * rinv;
            int c = c0 + wq * 64 + nf * 16 + lr;
            int m = m0 + wr * 128 + mf * 16 + lg * 4;
            *(f32x4*)(out + ((size_t)b * CDIM + c) * NPIX + m) = o;
        }
    }
}

extern "C" void kernel_launch(void* const* d_in, const int* in_sizes, int n_in,
                              void* d_out, int out_size, void* d_ws, size_t ws_size,
                              hipStream_t stream) {
    const float* x  = (const float*)d_in[0];
    const float* Wf = (const float*)d_in[1];
    const float* Wg = (const float*)d_in[2];
    const float* Wh = (const float*)d_in[3];
    unsigned short* ws = (unsigned short*)d_ws;
    _Float16* xT = (_Float16*)(ws + XT_OFF);
    _Float16* wh = (_Float16*)(ws + WH_OFF);
    float* Lp = (float*)(ws + LP_OFF);
    float* out = (float*)d_out;

    wcvt<<<320, 256, 0, stream>>>(Wf, Wg, Wh, wh);
    xcvt<<<dim3(16, 8, 32), 256, 0, stream>>>(x, xT);
    fg_mfma<<<256, 256, 0, stream>>>(wh, xT, ws);
    h_mfma<<<256, 512, 0, stream>>>(wh, xT, ws);
    attn_lp<<<2048, 256, 0, stream>>>(ws, Lp);
    attn_fused<<<256, 512, 0, stream>>>(ws, Lp, out);
}

// Round 12
// 113.162 us; speedup vs baseline: 1.1485x; 1.1485x over previous
//
#include <hip/hip_runtime.h>
#include <stdint.h>

#define CDIM 512
#define NPIX 1024
#define IDIM 64

// ws layout (ushort elements), ws_size = 256 MiB:
//   [0)       per-batch fgh: fT[1024][64] gT[1024][64] h[512][1024] bf16 (40 MB)
//   [XT_OFF)  xT[32][1024][512] fp16 + wh (dead after fgh_mfma)
//   [P_OFF=XT_OFF) P~[32][1024][1024] bf16 unnormalized (overlays xT+wh, 67 MB)
//   [LP_OFF)  Lp[4][32][1024] f32 partial row sums (512 KB)
#define WS_BATCH (65536 + 65536 + 524288)
#define XT_OFF   ((size_t)32 * WS_BATCH)
#define XT_ELEMS ((size_t)32 * 1024 * 512)
#define WH_OFF   (XT_OFF + XT_ELEMS)
#define P_OFF    XT_OFF
#define P_ELEMS  ((size_t)32 * 1024 * 1024)
#define LP_OFF   (P_OFF + P_ELEMS)

typedef __bf16 bf16x8 __attribute__((ext_vector_type(8)));
typedef _Float16 f16x8 __attribute__((ext_vector_type(8)));
typedef float f32x4 __attribute__((ext_vector_type(4)));
typedef unsigned short u16x8 __attribute__((ext_vector_type(8)));

__device__ __forceinline__ unsigned short f2bf(float f) {
    union { float f; uint32_t u; } v; v.f = f;
    uint32_t u = v.u;
    u += 0x7fffu + ((u >> 16) & 1u);   // RNE
    return (unsigned short)(u >> 16);
}

__device__ __forceinline__ f32x4 mfma_bf(bf16x8 a, bf16x8 b, f32x4 c) {
    return __builtin_amdgcn_mfma_f32_16x16x32_bf16(a, b, c, 0, 0, 0);
}
__device__ __forceinline__ f32x4 mfma_h(f16x8 a, f16x8 b, f32x4 c) {
    return __builtin_amdgcn_mfma_f32_16x16x32_f16(a, b, c, 0, 0, 0);
}
__device__ __forceinline__ void gld_lds16(const void* g, void* l) {
    __builtin_amdgcn_global_load_lds(
        (const __attribute__((address_space(1))) unsigned int*)g,
        (__attribute__((address_space(3))) unsigned int*)l,
        16, 0, 0);
}
__device__ __forceinline__ void barrier_mem() {
    asm volatile("" ::: "memory");
    __builtin_amdgcn_s_barrier();
    asm volatile("" ::: "memory");
}
// LDS read-side swizzle for [rows][32-elem] 2B tiles (64B rows)
__device__ __forceinline__ int swz(int by) { return by ^ (((by >> 7) & 3) << 4); }

// ---------------------------------------------------------------------------
// Prep (merged): x[b][c][n] fp32 -> xT[b][n][c] fp16, and (blockIdx.y==8)
// W fp32 -> wh[640][512] fp16.
// ---------------------------------------------------------------------------
__global__ __launch_bounds__(256) void xw_cvt(
    const float* __restrict__ x,
    const float* __restrict__ Wf, const float* __restrict__ Wg,
    const float* __restrict__ Wh,
    _Float16* __restrict__ xT, _Float16* __restrict__ wh)
{
    const int t = threadIdx.x;
    if (blockIdx.y == 8) {
        int wb = blockIdx.z * 16 + blockIdx.x;
        if (wb >= 320) return;
        int e = (wb * 256 + t) * 4;
        int r = e >> 9, k = e & 511;
        const float* src;
        if (r < 64)       src = Wf + (size_t)r * 512 + k;
        else if (r < 128) src = Wg + (size_t)(r - 64) * 512 + k;
        else              src = Wh + (size_t)(r - 128) * 512 + k;
        float4 v = *(const float4*)src;
        _Float16 h4[4] = {(_Float16)v.x, (_Float16)v.y, (_Float16)v.z, (_Float16)v.w};
        *(ushort4*)(wh + e) = *(ushort4*)h4;
        return;
    }
    __shared__ _Float16 tile[64][72];
    const int b = blockIdx.z, c0 = blockIdx.y * 64, n0 = blockIdx.x * 64;
    const float* xb = x + ((size_t)b * CDIM + c0) * NPIX + n0;
    #pragma unroll
    for (int p = 0; p < 4; ++p) {
        int ci = p * 16 + (t >> 4);
        int nj = (t & 15) * 4;
        float4 v = *(const float4*)(xb + (size_t)ci * NPIX + nj);
        tile[nj + 0][ci] = (_Float16)v.x;
        tile[nj + 1][ci] = (_Float16)v.y;
        tile[nj + 2][ci] = (_Float16)v.z;
        tile[nj + 3][ci] = (_Float16)v.w;
    }
    __syncthreads();
    _Float16* dst = xT + ((size_t)b * NPIX + n0) * CDIM + c0;
    #pragma unroll
    for (int p = 0; p < 2; ++p) {
        int n  = p * 32 + (t >> 3);
        int cc = (t & 7) * 8;
        ushort4 a  = *(ushort4*)&tile[n][cc];
        ushort4 bq = *(ushort4*)&tile[n][cc + 4];
        *(ushort4*)(dst + (size_t)n * CDIM + cc)     = a;
        *(ushort4*)(dst + (size_t)n * CDIM + cc + 4) = bq;
    }
}

// ---------------------------------------------------------------------------
// Kernel 1: MFMA projection GEMM (round-9-verified structure). Block 128r x
// 128n, BK=32, 4 waves, 2-deep pipeline, counted vmcnt, swizzled LDS, 4/CU.
// New: h-epilogue repacked through per-wave LDS scratch -> 16B coalesced
// stores (was 64 scalar u16 global stores per thread).
// Grid 1280 = 8 XCD x 160 (= 4 whole batches x 40 tiles).
// ---------------------------------------------------------------------------
__global__ __launch_bounds__(256, 4) void fgh_mfma(
    const _Float16* __restrict__ wh, const _Float16* __restrict__ xT,
    unsigned short* __restrict__ ws)
{
    const int orig = blockIdx.x;
    const int work = (orig & 7) * 160 + (orig >> 3);
    const int b    = work / 40;
    const int tile = work % 40;
    const int tr = tile >> 3, tn = tile & 7;

    const int t = threadIdx.x, lane = t & 63, w = t >> 6;
    const int lr = lane & 15, lg = lane >> 4;
    const int wr = w >> 1, wc = w & 1;

    // unified LDS: A dbuf [0,16K), B dbuf [16K,32K); epilogue scratch reuses all
    __shared__ __align__(16) char smem[36864];

    const _Float16* Ag = wh + (size_t)(tr * 128) * CDIM;
    const _Float16* Bg = xT + ((size_t)b * NPIX + tn * 128) * CDIM;

    int offA[4], offB[4];
    #pragma unroll
    for (int mf = 0; mf < 4; ++mf)
        offA[mf] = swz((wr * 64 + mf * 16 + lr) * 64 + lg * 16);
    #pragma unroll
    for (int nf = 0; nf < 4; ++nf)
        offB[nf] = swz((wc * 64 + nf * 16 + lr) * 64 + lg * 16);

    f32x4 acc[4][4];
    #pragma unroll
    for (int i = 0; i < 4; ++i)
        #pragma unroll
        for (int j = 0; j < 4; ++j) acc[i][j] = (f32x4){0.f, 0.f, 0.f, 0.f};

    auto stage = [&](int buf, int k0) {
        #pragma unroll
        for (int p = 0; p < 2; ++p) {
            int q = p * 256 + t;
            gld_lds16(Ag + (size_t)(q >> 2) * CDIM + k0 + ((q & 3) ^ ((q >> 3) & 3)) * 8,
                      smem + buf * 8192 + q * 16);
        }
        #pragma unroll
        for (int p = 0; p < 2; ++p) {
            int q = p * 256 + t;
            gld_lds16(Bg + (size_t)(q >> 2) * CDIM + k0 + ((q & 3) ^ ((q >> 3) & 3)) * 8,
                      smem + 16384 + buf * 8192 + q * 16);
        }
    };

    stage(0, 0);
    stage(1, 32);

    #pragma unroll 1
    for (int ks = 0; ks < 16; ++ks) {
        const int cur = ks & 1;
        if (ks < 15) asm volatile("s_waitcnt vmcnt(4)" ::: "memory");
        else         asm volatile("s_waitcnt vmcnt(0)" ::: "memory");
        barrier_mem();

        const char* Ab = smem + cur * 8192;
        const char* Bb = smem + 16384 + cur * 8192;
        f16x8 af[4];
        #pragma unroll
        for (int mf = 0; mf < 4; ++mf)
            af[mf] = *(const f16x8*)(Ab + offA[mf]);
        #pragma unroll
        for (int nf = 0; nf < 4; ++nf) {
            f16x8 bv = *(const f16x8*)(Bb + offB[nf]);
            #pragma unroll
            for (int mf = 0; mf < 4; ++mf)
                acc[mf][nf] = mfma_h(af[mf], bv, acc[mf][nf]);
        }

        barrier_mem();
        if (ks + 2 < 16) stage(cur, (ks + 2) * 32);
    }
    // after final barrier all waves are done with the staging buffers

    unsigned short* base = ws + (size_t)b * WS_BATCH;
    const int nbase = tn * 128 + wc * 64;
    if (tr == 0) {
        // wr=0 -> f rows 0..63, wr=1 -> g rows 0..63; store transposed [n][i]
        unsigned short* dst = base + (wr ? 65536 : 0);
        #pragma unroll
        for (int mf = 0; mf < 4; ++mf) {
            const int i0 = mf * 16 + lg * 4;
            #pragma unroll
            for (int nf = 0; nf < 4; ++nf) {
                int n = nbase + nf * 16 + lr;
                ushort4 v;
                v.x = f2bf(acc[mf][nf][0]); v.y = f2bf(acc[mf][nf][1]);
                v.z = f2bf(acc[mf][nf][2]); v.w = f2bf(acc[mf][nf][3]);
                *(ushort4*)(dst + (size_t)n * 64 + i0) = v;
            }
        }
    } else {
        // repack h quadrant (64c x 64n) via per-wave scratch [64][72] ushort,
        // then coalesced 16B stores. Mapping element-identical to round 9:
        // c = cbase + mf*16 + lg*4 + j, n = nbase + nf*16 + lr.
        unsigned short* sc = (unsigned short*)smem + w * 4608;   // 64*72
        #pragma unroll
        for (int mf = 0; mf < 4; ++mf)
            #pragma unroll
            for (int nf = 0; nf < 4; ++nf)
                #pragma unroll
                for (int j = 0; j < 4; ++j)
                    sc[(mf * 16 + lg * 4 + j) * 72 + nf * 16 + lr] =
                        f2bf(acc[mf][nf][j]);
        unsigned short* hd = base + 131072;
        const int cbase = (tr - 1) * 128 + wr * 64;
        #pragma unroll
        for (int ii = 0; ii < 8; ++ii) {
            int cl = ii * 8 + (lane >> 3);
            int nl = (lane & 7) * 8;
            u16x8 v = *(const u16x8*)&sc[cl * 72 + nl];   // 16B-aligned (144|16)
            *(u16x8*)(hd + (size_t)(cbase + cl) * NPIX + nbase + nl) = v;
        }
    }
}

// ---------------------------------------------------------------------------
// Kernel 2: UNNORMALIZED P~ = exp(g^T f) + partial row sums (round-9 exact).
// ---------------------------------------------------------------------------
__global__ __launch_bounds__(256, 3) void attn_sm(
    const unsigned short* __restrict__ ws, unsigned short* __restrict__ P,
    float* __restrict__ Lp)
{
    const int orig = blockIdx.x;
    const int work = (orig & 7) * 256 + (orig >> 3);
    const int b    = work >> 6;
    const int tile = work & 63;
    const int mt = tile >> 2, nt = tile & 3;
    const int m0 = mt * 64, n0 = nt * 256;

    const int t = threadIdx.x, lane = t & 63, w = t >> 6;
    const int lr = lane & 15, lg = lane >> 4;

    const unsigned short* fT = ws + (size_t)b * WS_BATCH;
    const unsigned short* gT = fT + 65536;

    __shared__ unsigned short Ab[2][64 * 32];
    __shared__ unsigned short Bb[2][256 * 32];
    __shared__ float red[4][64];
    __shared__ unsigned short rp[4][16][72];

    #pragma unroll
    for (int kc = 0; kc < 2; ++kc) {
        {
            int q = t;
            gld_lds16(gT + (size_t)(m0 + (q >> 2)) * 64 + kc * 32 + ((q & 3) ^ ((q >> 3) & 3)) * 8,
                      (char*)&Ab[kc][0] + q * 16);
        }
        #pragma unroll
        for (int p = 0; p < 4; ++p) {
            int q = p * 256 + t;
            gld_lds16(fT + (size_t)(n0 + (q >> 2)) * 64 + kc * 32 + ((q & 3) ^ ((q >> 3) & 3)) * 8,
                      (char*)&Bb[kc][0] + q * 16);
        }
    }
    __syncthreads();

    int offA[4], offB[4];
    #pragma unroll
    for (int mf = 0; mf < 4; ++mf)
        offA[mf] = swz((mf * 16 + lr) * 64 + lg * 16);
    #pragma unroll
    for (int nf = 0; nf < 4; ++nf)
        offB[nf] = swz((w * 64 + nf * 16 + lr) * 64 + lg * 16);

    f32x4 acc[4][4];
    #pragma unroll
    for (int i = 0; i < 4; ++i)
        #pragma unroll
        for (int j = 0; j < 4; ++j) acc[i][j] = (f32x4){0.f, 0.f, 0.f, 0.f};

    #pragma unroll
    for (int kc = 0; kc < 2; ++kc) {
        const char* Abc = (const char*)&Ab[kc][0];
        const char* Bbc = (const char*)&Bb[kc][0];
        bf16x8 af[4];
        #pragma unroll
        for (int mf = 0; mf < 4; ++mf)
            af[mf] = *(const bf16x8*)(Abc + offA[mf]);
        #pragma unroll
        for (int nf = 0; nf < 4; ++nf) {
            bf16x8 bv = *(const bf16x8*)(Bbc + offB[nf]);
            #pragma unroll
            for (int mf = 0; mf < 4; ++mf)
                acc[mf][nf] = mfma_bf(af[mf], bv, acc[mf][nf]);
        }
    }

    #pragma unroll
    for (int mf = 0; mf < 4; ++mf) {
        #pragma unroll
        for (int j = 0; j < 4; ++j) {
            float s = 0.f;
            #pragma unroll
            for (int nf = 0; nf < 4; ++nf) {
                float e = __expf(acc[mf][nf][j]);
                acc[mf][nf][j] = e;
                s += e;
            }
            s += __shfl_xor(s, 1);
            s += __shfl_xor(s, 2);
            s += __shfl_xor(s, 4);
            s += __shfl_xor(s, 8);
            if (lr == 0) red[w][mf * 16 + lg * 4 + j] = s;
        }
    }
    __syncthreads();
    if (t < 64) {
        float s = red[0][t] + red[1][t] + red[2][t] + red[3][t];
        Lp[(size_t)nt * 32768 + (size_t)b * 1024 + m0 + t] = s;
    }

    unsigned short* Pb = P + (size_t)b * NPIX * NPIX;
    #pragma unroll
    for (int mf = 0; mf < 4; ++mf) {
        #pragma unroll
        for (int nf = 0; nf < 4; ++nf)
            #pragma unroll
            for (int j = 0; j < 4; ++j)
                rp[w][lg * 4 + j][nf * 16 + lr] = f2bf(acc[mf][nf][j]);
        #pragma unroll
        for (int ii = 0; ii < 2; ++ii) {
            int row = ii * 8 + (lane >> 3);
            int ch  = lane & 7;
            ushort4 v0 = *(ushort4*)&rp[w][row][ch * 8];
            ushort4 v1 = *(ushort4*)&rp[w][row][ch * 8 + 4];
            unsigned short* dst = Pb + (size_t)(m0 + mf * 16 + row) * NPIX
                                     + n0 + w * 64 + ch * 8;
            *(ushort4*)(dst)     = v0;
            *(ushort4*)(dst + 4) = v1;
        }
    }
}

// ---------------------------------------------------------------------------
// Kernel 3 (8-phase): O[m][c] = (1/L[m]) sum_n P~[m][n] h[c][n].
// Round-9-verified. Block 256m x 256c, BK=64, 8 waves, 1 block/CU.
// ---------------------------------------------------------------------------
__global__ __launch_bounds__(512, 2) void attn_pv(
    const unsigned short* __restrict__ P, const unsigned short* __restrict__ ws,
    const float* __restrict__ Lp, float* __restrict__ out)
{
    const int orig = blockIdx.x;
    const int work = (orig & 7) * 32 + (orig >> 3);
    const int b    = work >> 3;
    const int tile = work & 7;
    const int m0   = (tile >> 1) * 256;
    const int c0   = (tile & 1) * 256;

    const int t = threadIdx.x, lane = t & 63, w = t >> 6;
    const int lr = lane & 15, lg = lane >> 4;
    const int wr = w >> 2, wc = w & 3;

    __shared__ __align__(16) char smem[131072];

    const unsigned short* Ag = P + ((size_t)b * NPIX + m0) * NPIX;
    const unsigned short* Bg = ws + (size_t)b * WS_BATCH + 131072 + (size_t)c0 * NPIX;

    const int sk0 = ((lg) ^ (lr & 7)) * 16;
    const int sk1 = ((4 + lg) ^ (lr & 7)) * 16;
    const int rAbase = (wr * 128 + lr) * 128;
    const int rBbase = (wc * 64 + lr) * 128;

    f32x4 acc[8][4];
    #pragma unroll
    for (int i = 0; i < 8; ++i)
        #pragma unroll
        for (int j = 0; j < 4; ++j) acc[i][j] = (f32x4){0.f, 0.f, 0.f, 0.f};

    auto stage_half = [&](int buf, int isB, int half, int kt) {
        const unsigned short* G = isB ? Bg : Ag;
        char* L = smem + isB * 65536 + buf * 32768 + half * 16384;
        #pragma unroll
        for (int l = 0; l < 2; ++l) {
            int q = l * 512 + t;
            gld_lds16(G + (size_t)(half * 128 + (q >> 3)) * NPIX + kt * 64
                        + (((q & 7) ^ ((q >> 3) & 7)) * 8),
                      L + q * 16);
        }
    };

    stage_half(0, 0, 0, 0); stage_half(0, 0, 1, 0);
    stage_half(0, 1, 0, 0); stage_half(0, 1, 1, 0);
    stage_half(1, 1, 0, 1); stage_half(1, 1, 1, 1);
    asm volatile("s_waitcnt vmcnt(4)" ::: "memory");
    barrier_mem();

    bf16x8 bfr[4][2];

    #pragma unroll 1
    for (int j = 0; j < 8; ++j) {
        const bool nl = (j < 7);
        #pragma unroll
        for (int grp = 0; grp < 2; ++grp) {
            const char* Abase = smem + grp * 32768;
            const char* Bbase = smem + 65536 + grp * 32768;
            #pragma unroll
            for (int p = 0; p < 4; ++p) {
                if (p == 0) {
                    #pragma unroll
                    for (int nf = 0; nf < 4; ++nf) {
                        bfr[nf][0] = *(const bf16x8*)(Bbase + rBbase + nf * 2048 + sk0);
                        bfr[nf][1] = *(const bf16x8*)(Bbase + rBbase + nf * 2048 + sk1);
                    }
                }
                bf16x8 af[2][2];
                #pragma unroll
                for (int e = 0; e < 2; ++e) {
                    af[e][0] = *(const bf16x8*)(Abase + rAbase + (p * 2 + e) * 2048 + sk0);
                    af[e][1] = *(const bf16x8*)(Abase + rAbase + (p * 2 + e) * 2048 + sk1);
                }
                if (grp == 0) {
                    if (p == 0) stage_half(1, 0, 0, 2 * j + 1);
                    if (p == 1) stage_half(1, 0, 1, 2 * j + 1);
                    if (p == 2 && nl) stage_half(0, 1, 0, 2 * j + 2);
                    if (p == 3 && nl) stage_half(0, 1, 1, 2 * j + 2);
                } else {
                    if (p == 0 && nl) stage_half(0, 0, 0, 2 * j + 2);
                    if (p == 1 && nl) stage_half(0, 0, 1, 2 * j + 2);
                    if (p == 2 && nl) stage_half(1, 1, 0, 2 * j + 3);
                    if (p == 3 && nl) stage_half(1, 1, 1, 2 * j + 3);
                }
                if (p == 3) {
                    if (nl) asm volatile("s_waitcnt vmcnt(4)" ::: "memory");
                    else    asm volatile("s_waitcnt vmcnt(0)" ::: "memory");
                }
                barrier_mem();
                __builtin_amdgcn_s_setprio(1);
                #pragma unroll
                for (int ks = 0; ks < 2; ++ks)
                    #pragma unroll
                    for (int e = 0; e < 2; ++e)
                        #pragma unroll
                        for (int nf = 0; nf < 4; ++nf)
                            acc[p * 2 + e][nf] =
                                mfma_bf(af[e][ks], bfr[nf][ks], acc[p * 2 + e][nf]);
                __builtin_amdgcn_s_setprio(0);
            }
        }
    }

    #pragma unroll
    for (int mf = 0; mf < 8; ++mf) {
        const size_t mi = (size_t)b * 1024 + m0 + wr * 128 + mf * 16 + lg * 4;
        f32x4 L = *(const f32x4*)&Lp[mi]
                + *(const f32x4*)&Lp[32768 + mi]
                + *(const f32x4*)&Lp[65536 + mi]
                + *(const f32x4*)&Lp[98304 + mi];
        f32x4 rinv;
        #pragma unroll
        for (int j = 0; j < 4; ++j) rinv[j] = 1.0f / L[j];
        #pragma unroll
        for (int nf = 0; nf < 4; ++nf) {
            f32x4 o = acc[mf][nf] * rinv;
            int c = c0 + wc * 64 + nf * 16 + lr;
            int m = m0 + wr * 128 + mf * 16 + lg * 4;
            *(f32x4*)(out + ((size_t)b * CDIM + c) * NPIX + m) = o;
        }
    }
}

extern "C" void kernel_launch(void* const* d_in, const int* in_sizes, int n_in,
                              void* d_out, int out_size, void* d_ws, size_t ws_size,
                              hipStream_t stream) {
    const float* x  = (const float*)d_in[0];
    const float* Wf = (const float*)d_in[1];
    const float* Wg = (const float*)d_in[2];
    const float* Wh = (const float*)d_in[3];
    unsigned short* ws = (unsigned short*)d_ws;   // ~110 MB used (ws = 256 MiB)
    _Float16* xT = (_Float16*)(ws + XT_OFF);
    _Float16* wh = (_Float16*)(ws + WH_OFF);
    unsigned short* P = ws + P_OFF;               // overlays xT+wh (dead by then)
    float* Lp = (float*)(ws + LP_OFF);
    float* out = (float*)d_out;

    xw_cvt<<<dim3(16, 9, 32), 256, 0, stream>>>(x, Wf, Wg, Wh, xT, wh);
    fgh_mfma<<<1280, 256, 0, stream>>>(wh, xT, ws);
    attn_sm<<<2048, 256, 0, stream>>>(ws, P, Lp);
    attn_pv<<<256, 512, 0, stream>>>(P, ws, Lp, out);
}